// Round 7
// baseline (357.477 us; speedup 1.0000x reference)
//
#include <hip/hip_runtime.h>
#include <hip/hip_bf16.h>
#include <math.h>

constexpr int kBS = 2;
constexpr int kNQ = 20197;
constexpr int kNV = 20197;
constexpr int kM  = kBS * kNQ;   // 40394
constexpr int kMpad = 40448;     // 158*256, slack rows for mid_b

__constant__ int cLH[4] = {100, 50, 25, 13};
__constant__ int cLW[4] = {152, 76, 38, 19};
__constant__ int cLS[4] = {0, 15200, 19000, 19950};

typedef __bf16 bf16x8 __attribute__((ext_vector_type(8)));
typedef float  f32x4  __attribute__((ext_vector_type(4)));
typedef unsigned uintx4 __attribute__((ext_vector_type(4)));

__device__ __forceinline__ unsigned short f2bf(float x) {
    unsigned u = __float_as_uint(x);
    return (unsigned short)((u + 0x7fffu + ((u >> 16) & 1u)) >> 16);
}
__device__ __forceinline__ unsigned pack2(float a, float b) {
    return (unsigned)f2bf(a) | ((unsigned)f2bf(b) << 16);
}
__device__ __forceinline__ float bflo(unsigned u) { return __uint_as_float(u << 16); }
__device__ __forceinline__ float bfhi(unsigned u) { return __uint_as_float(u & 0xffff0000u); }

// ---------------------------------------------------------------------------
// prep_w: weight transposes (fp32 KxN -> bf16 NxK) + fused bias384.
// ---------------------------------------------------------------------------
__global__ __launch_bounds__(256) void prep_w(
    const float* __restrict__ Wv, const float* __restrict__ Wso,
    const float* __restrict__ Waw, const float* __restrict__ Wo,
    const float* __restrict__ bso, const float* __restrict__ baw,
    unsigned short* __restrict__ WvT, unsigned short* __restrict__ WsoawT,
    unsigned short* __restrict__ WoT, float* __restrict__ bias384)
{
    int k = blockIdx.x * 256 + threadIdx.x;
    if (k < 65536) { WvT[k] = f2bf(Wv[(k & 255) * 256 + (k >> 8)]); return; }
    k -= 65536;
    if (k < 98304) {
        int n = k >> 8, kk = k & 255;
        WsoawT[k] = f2bf(n < 256 ? Wso[kk * 256 + n] : Waw[kk * 128 + (n - 256)]);
        return;
    }
    k -= 98304;
    if (k < 65536) { WoT[k] = f2bf(Wo[(k & 255) * 256 + (k >> 8)]); return; }
    k -= 65536;
    if (k < 384) bias384[k] = (k < 256) ? bso[k] : baw[k - 256];
}

// ---------------------------------------------------------------------------
// REG-B GEMM for the two input GEMMs, one dispatch, no LDS, no barriers.
// Each wave holds its n-64 x K256 slice of B^T in 128 VGPRs (32 bf16x8
// frags), then streams m-16-tiles: A-frag fp32 loaded direct from global,
// packed to bf16 in-reg, 4 MFMA per k-step. 474 blocks = 1 occupancy round.
//   bx <158 : v_b[:,0:256]   = value @ WvT^T  + bv    (16 m-tiles/block)
//   bx <316 : soaw[:,0:256]  = query @ WsoawT^T + b384 (16 m-tiles)
//   bx <474 : soaw[:,256:384] = query @ ... (waves pair-split n/m, 8 tiles)
// ---------------------------------------------------------------------------
__global__ __launch_bounds__(256, 2) void gemm_fused(
    const float* __restrict__ value, const float* __restrict__ query,
    const __hip_bfloat16* __restrict__ WvT, const __hip_bfloat16* __restrict__ WsoawT,
    const float* __restrict__ bv, const float* __restrict__ b384,
    unsigned short* __restrict__ v_b, unsigned short* __restrict__ soaw)
{
    const int bx = blockIdx.x, t = threadIdx.x;
    const int wave = t >> 6, lane = t & 63, quad = lane >> 4, l16 = lane & 15;

    const float* A; const __hip_bfloat16* BT; const float* bias; unsigned short* C;
    int N, n0w, mstart, ntiles;
    if (bx < 158)      { A = value; BT = WvT;    bias = bv;   C = v_b;  N = 256;
                         n0w = wave * 64; mstart = bx * 256; ntiles = 16; }
    else if (bx < 316) { A = query; BT = WsoawT; bias = b384; C = soaw; N = 384;
                         n0w = wave * 64; mstart = (bx - 158) * 256; ntiles = 16; }
    else               { A = query; BT = WsoawT; bias = b384; C = soaw; N = 384;
                         n0w = 256 + (wave & 1) * 64;
                         mstart = (bx - 316) * 256 + (wave >> 1) * 128; ntiles = 8; }

    // B^T slice -> registers (once per block; L2-hot weights)
    bf16x8 Bf[4][8];
    #pragma unroll
    for (int nt = 0; nt < 4; ++nt)
        #pragma unroll
        for (int kc = 0; kc < 8; ++kc)
            Bf[nt][kc] = *(const bf16x8*)(const void*)
                (BT + (size_t)(n0w + nt * 16 + l16) * 256 + kc * 32 + quad * 8);

    for (int it = 0; it < ntiles; ++it) {
        const int m0 = mstart + it * 16;
        const int arow = min(m0 + l16, kM - 1);   // clamp: dup rows masked at store
        const float* ap = A + (size_t)arow * 256 + quad * 8;
        float4 a0[8], a1[8];
        #pragma unroll
        for (int kc = 0; kc < 8; ++kc) {
            a0[kc] = *(const float4*)(ap + kc * 32);
            a1[kc] = *(const float4*)(ap + kc * 32 + 4);
        }
        f32x4 acc[4] = {};
        #pragma unroll
        for (int kc = 0; kc < 8; ++kc) {
            uintx4 u = { pack2(a0[kc].x, a0[kc].y), pack2(a0[kc].z, a0[kc].w),
                         pack2(a1[kc].x, a1[kc].y), pack2(a1[kc].z, a1[kc].w) };
            bf16x8 af = __builtin_bit_cast(bf16x8, u);
            #pragma unroll
            for (int nt = 0; nt < 4; ++nt)
                acc[nt] = __builtin_amdgcn_mfma_f32_16x16x32_bf16(
                    af, Bf[nt][kc], acc[nt], 0, 0, 0);
        }
        #pragma unroll
        for (int nt = 0; nt < 4; ++nt) {
            const int col = n0w + nt * 16 + l16;
            const float bvv = bias[col];
            #pragma unroll
            for (int i = 0; i < 4; ++i) {
                const int row = m0 + quad * 4 + i;
                if (row < kM)
                    C[(size_t)row * N + col] = f2bf(acc[nt][i] + bvv);
            }
        }
    }
}

// ---------------------------------------------------------------------------
// REG-B final GEMM: out = mid_b(bf16) @ WoT^T + bo + query (fp32 out).
// A is bf16 with kMpad slack rows (direct bf16x8 frag loads, no clamp).
// ---------------------------------------------------------------------------
__global__ __launch_bounds__(256, 2) void gemm_final(
    const unsigned short* __restrict__ mid_b, const __hip_bfloat16* __restrict__ WoT,
    const float* __restrict__ bo, const float* __restrict__ query,
    float* __restrict__ out)
{
    const int bx = blockIdx.x, t = threadIdx.x;
    const int wave = t >> 6, lane = t & 63, quad = lane >> 4, l16 = lane & 15;
    const int n0w = wave * 64, mstart = bx * 128;

    bf16x8 Bf[4][8];
    #pragma unroll
    for (int nt = 0; nt < 4; ++nt)
        #pragma unroll
        for (int kc = 0; kc < 8; ++kc)
            Bf[nt][kc] = *(const bf16x8*)(const void*)
                (WoT + (size_t)(n0w + nt * 16 + l16) * 256 + kc * 32 + quad * 8);

    for (int it = 0; it < 8; ++it) {
        const int m0 = mstart + it * 16;
        const __hip_bfloat16* ap =
            (const __hip_bfloat16*)mid_b + (size_t)(m0 + l16) * 256 + quad * 8;
        bf16x8 af[8];
        #pragma unroll
        for (int kc = 0; kc < 8; ++kc)
            af[kc] = *(const bf16x8*)(const void*)(ap + kc * 32);
        f32x4 acc[4] = {};
        #pragma unroll
        for (int kc = 0; kc < 8; ++kc)
            #pragma unroll
            for (int nt = 0; nt < 4; ++nt)
                acc[nt] = __builtin_amdgcn_mfma_f32_16x16x32_bf16(
                    af[kc], Bf[nt][kc], acc[nt], 0, 0, 0);
        #pragma unroll
        for (int nt = 0; nt < 4; ++nt) {
            const int col = n0w + nt * 16 + l16;
            const float bvv = bo[col];
            #pragma unroll
            for (int i = 0; i < 4; ++i) {
                const int row = m0 + quad * 4 + i;
                if (row < kM)
                    out[(size_t)row * 256 + col] =
                        acc[nt][i] + bvv + query[(size_t)row * 256 + col];
            }
        }
    }
}

// ---------------------------------------------------------------------------
// Sampler: byte-identical to R6 (90.8 us measured) — FROZEN.
// ---------------------------------------------------------------------------
__global__ __launch_bounds__(128) void msda_sample(
    const __hip_bfloat16* __restrict__ v,     // (BS*NV, 256) bf16
    const __hip_bfloat16* __restrict__ soaw,  // (M, 384) bf16: so | logits
    const float* __restrict__ rp,             // (M, 4, 2)
    __hip_bfloat16* __restrict__ mid)         // (kMpad, 256) bf16
{
    const int bq = blockIdx.x;
    const int b  = bq >= kNQ;
    const int t  = threadIdx.x;

    __shared__ int   sOff[128 * 5];
    __shared__ float sW[128 * 5];

    {   // phase 1
        const int h = t >> 4, lp = t & 15, l = lp >> 2;
        unsigned sopk = *(const unsigned*)(const void*)(soaw + (size_t)bq * 384 + 2 * t);
        float logit = bflo((unsigned)*(const unsigned short*)(const void*)
                           (soaw + (size_t)bq * 384 + 256 + t));
        float2 rr = *(const float2*)(rp + (size_t)bq * 8 + l * 2);
        float sx = bflo(sopk), sy = bfhi(sopk);

        float mx = logit;
        #pragma unroll
        for (int s = 8; s >= 1; s >>= 1) mx = fmaxf(mx, __shfl_xor(mx, s, 16));
        float e = __expf(logit - mx);
        float sum = e;
        #pragma unroll
        for (int s = 8; s >= 1; s >>= 1) sum += __shfl_xor(sum, s, 16);
        float w = e / sum;

        const int ww = cLW[l], hh = cLH[l];
        const float fw = (float)ww, fh = (float)hh;
        float x = rr.x * fw + sx - 0.5f;   // == (rx + so/w)*w - 0.5
        float y = rr.y * fh + sy - 0.5f;
        float xf = floorf(x), yf = floorf(y);
        int x0 = (int)xf, y0 = (int)yf;
        float wx1 = x - xf, wx0 = 1.f - wx1;
        float wy1 = y - yf, wy0 = 1.f - wy1;
        bool vx0 = (x0 >= 0) & (x0 < ww);
        bool vx1 = (x0 >= -1) & (x0 + 1 < ww);
        bool vy0 = (y0 >= 0) & (y0 < hh);
        bool vy1 = (y0 >= -1) & (y0 + 1 < hh);
        int cx0 = min(max(x0, 0), ww - 1);
        int cx1 = min(max(x0 + 1, 0), ww - 1);
        int cy0 = min(max(y0, 0), hh - 1);
        int cy1 = min(max(y0 + 1, 0), hh - 1);
        const int base = cLS[l] * 256 + h * 32;
        sOff[t * 5 + 0] = base + (cy0 * ww + cx0) * 256;
        sOff[t * 5 + 1] = base + (cy0 * ww + cx1) * 256;
        sOff[t * 5 + 2] = base + (cy1 * ww + cx0) * 256;
        sOff[t * 5 + 3] = base + (cy1 * ww + cx1) * 256;
        sW[t * 5 + 0] = (vx0 & vy0) ? w * wx0 * wy0 : 0.f;
        sW[t * 5 + 1] = (vx1 & vy0) ? w * wx1 * wy0 : 0.f;
        sW[t * 5 + 2] = (vx0 & vy1) ? w * wx0 * wy1 : 0.f;
        sW[t * 5 + 3] = (vx1 & vy1) ? w * wx1 * wy1 : 0.f;
    }
    __syncthreads();

    // phase 2
    const int h = t >> 4, c = (t & 15) * 2;
    const __hip_bfloat16* vb = v + (size_t)b * kNV * 256 + c;
    float accx = 0.f, accy = 0.f;
    const int p0 = h * 16;
    #pragma unroll 4
    for (int pp = 0; pp < 16; ++pp) {
        const int idx = (p0 + pp) * 5;
        #pragma unroll
        for (int k2 = 0; k2 < 4; ++k2) {
            float wgt = sW[idx + k2];
            int   off = sOff[idx + k2];
            unsigned u = *(const unsigned*)(const void*)(vb + off);
            accx += wgt * bflo(u);
            accy += wgt * bfhi(u);
        }
    }
    *(unsigned*)(void*)(mid + (size_t)bq * 256 + h * 32 + c) = pack2(accx, accy);
}

// ---------------------------------------------------------------------------
extern "C" void kernel_launch(void* const* d_in, const int* in_sizes, int n_in,
                              void* d_out, int out_size, void* d_ws, size_t ws_size,
                              hipStream_t stream)
{
    const float* query = (const float*)d_in[0];
    const float* value = (const float*)d_in[1];
    const float* rp    = (const float*)d_in[2];
    const float* Wv  = (const float*)d_in[5];
    const float* bv  = (const float*)d_in[6];
    const float* Wso = (const float*)d_in[7];
    const float* bso = (const float*)d_in[8];
    const float* Waw = (const float*)d_in[9];
    const float* baw = (const float*)d_in[10];
    const float* Wo  = (const float*)d_in[11];
    const float* bo  = (const float*)d_in[12];

    // d_out overlay: v_b bf16 (kM*512 B) in first half; dead before the
    // final GEMM rewrites all of d_out.
    unsigned short* v_b = (unsigned short*)d_out;

    // ws: soaw bf16 (kM*384) | mid_b bf16 (kMpad*256, slack rows read by
    // final-GEMM A-frags, masked at epilogue) | WvT | WsoawT | WoT | bias384
    char* p = (char*)d_ws;
    __hip_bfloat16* soaw  = (__hip_bfloat16*)p;  p += (size_t)kM * 384 * 2;
    unsigned short* mid_b = (unsigned short*)p;  p += (size_t)kMpad * 256 * 2;
    unsigned short* WvT    = (unsigned short*)p; p += 256 * 256 * 2;
    unsigned short* WsoawT = (unsigned short*)p; p += 384 * 256 * 2;
    unsigned short* WoT    = (unsigned short*)p; p += 256 * 256 * 2;
    float* bias384         = (float*)p;

    hipLaunchKernelGGL(prep_w, dim3(898), dim3(256), 0, stream,
                       Wv, Wso, Waw, Wo, bso, baw, WvT, WsoawT, WoT, bias384);

    hipLaunchKernelGGL(gemm_fused, dim3(474), dim3(256), 0, stream,
                       value, query, (const __hip_bfloat16*)WvT,
                       (const __hip_bfloat16*)WsoawT, bv, bias384,
                       v_b, (unsigned short*)soaw);

    hipLaunchKernelGGL(msda_sample, dim3(kM), dim3(128), 0, stream,
                       (const __hip_bfloat16*)v_b, soaw, rp, (__hip_bfloat16*)mid_b);

    hipLaunchKernelGGL(gemm_final, dim3(316), dim3(256), 0, stream,
                       mid_b, (const __hip_bfloat16*)WoT, bo, query, (float*)d_out);
}